// Round 1
// baseline (333.203 us; speedup 1.0000x reference)
//
#include <hip/hip_runtime.h>
#include <hip/hip_bf16.h>

typedef __bf16 bf16_t;
typedef __attribute__((ext_vector_type(8))) __bf16 bf16x8;
typedef __attribute__((ext_vector_type(4))) __bf16 bf16x4;
typedef __attribute__((ext_vector_type(4))) float f32x4;

#define LOG2E 1.44269504088896340736f

// ---------------------------------------------------------------------------
// fp32 -> bf16 convert (vectorized x4)
// ---------------------------------------------------------------------------
__global__ void cvt_kernel(const float* __restrict__ in, bf16_t* __restrict__ out, int n4) {
    int i = blockIdx.x * 256 + threadIdx.x;
    if (i < n4) {
        float4 v = ((const float4*)in)[i];
        bf16x4 o = {(bf16_t)v.x, (bf16_t)v.y, (bf16_t)v.z, (bf16_t)v.w};
        ((bf16x4*)out)[i] = o;
    }
}

// ---------------------------------------------------------------------------
// Patch-embed GEMM: tok[4096,768] = patches[4096,256] @ proj_w[768,256]^T + b
// Patchify done on the fly while staging A into LDS. Single-shot K=256.
// Grid: (64 m-tiles, 12 n-tiles), 256 threads.
// ---------------------------------------------------------------------------
__global__ __launch_bounds__(256) void patch_gemm(const float* __restrict__ x,
                                                  const bf16_t* __restrict__ pw,
                                                  const float* __restrict__ pb,
                                                  float* __restrict__ tok) {
    const int bm = blockIdx.x;   // token tile (64 tokens)
    const int bn = blockIdx.y;   // embed tile (64 cols)
    const int tid = threadIdx.x;

    __shared__ bf16_t At[64][264];  // 256 + 8 pad
    __shared__ bf16_t Bt[64][264];

    // stage A: 64 tokens x 256 patch elems, patchify from x (1024x1024)
    #pragma unroll
    for (int t = 0; t < 16; t++) {
        int linear = tid + t * 256;       // 0..4095, vec4 granularity
        int ml = linear >> 6;             // token within tile
        int kv = (linear & 63) << 2;      // k offset (multiple of 4)
        int n = bm * 64 + ml;
        int pr = n >> 6, pc = n & 63;
        int i = kv >> 4, j = kv & 15;
        float4 v = *(const float4*)(x + (pr * 16 + i) * 1024 + pc * 16 + j);
        bf16x4 o = {(bf16_t)v.x, (bf16_t)v.y, (bf16_t)v.z, (bf16_t)v.w};
        *(bf16x4*)(&At[ml][kv]) = o;
    }
    // stage B: proj_w bf16 rows bn*64..+63, 256 k each (copy 16B chunks)
    #pragma unroll
    for (int t = 0; t < 8; t++) {
        int linear = tid + t * 256;       // 0..2047, vec8 granularity
        int nl = linear >> 5;             // 32 vec8 per row
        int kv = (linear & 31) << 3;
        *(int4*)(&Bt[nl][kv]) = *(const int4*)(pw + (size_t)(bn * 64 + nl) * 256 + kv);
    }
    __syncthreads();

    const int lane = tid & 63, wid = tid >> 6, ln = lane & 15, quad = lane >> 4;
    f32x4 acc[4];
    #pragma unroll
    for (int s = 0; s < 4; s++) acc[s] = {0.f, 0.f, 0.f, 0.f};

    #pragma unroll
    for (int kk = 0; kk < 8; kk++) {
        bf16x8 af = *(const bf16x8*)(&At[wid * 16 + ln][kk * 32 + quad * 8]);
        #pragma unroll
        for (int s = 0; s < 4; s++) {
            bf16x8 bfr = *(const bf16x8*)(&Bt[s * 16 + ln][kk * 32 + quad * 8]);
            acc[s] = __builtin_amdgcn_mfma_f32_16x16x32_bf16(af, bfr, acc[s], 0, 0, 0);
        }
    }

    #pragma unroll
    for (int s = 0; s < 4; s++) {
        int e = bn * 64 + s * 16 + ln;
        float bias = pb[e];
        #pragma unroll
        for (int r = 0; r < 4; r++) {
            int m = bm * 64 + wid * 16 + quad * 4 + r;
            tok[(size_t)m * 768 + e] = acc[s][r] + bias;
        }
    }
}

// ---------------------------------------------------------------------------
// LayerNorm per token (768), fp32 stats, bf16 out. Grid: 4096 blocks x 256.
// ---------------------------------------------------------------------------
__global__ __launch_bounds__(256) void ln_kernel(const float* __restrict__ tok,
                                                 const float* __restrict__ g,
                                                 const float* __restrict__ b,
                                                 bf16_t* __restrict__ out) {
    const int n = blockIdx.x;
    const int tid = threadIdx.x;
    const float* row = tok + (size_t)n * 768;
    float x0 = row[tid], x1 = row[tid + 256], x2 = row[tid + 512];
    float s = x0 + x1 + x2;
    float s2 = x0 * x0 + x1 * x1 + x2 * x2;
    #pragma unroll
    for (int off = 32; off; off >>= 1) {
        s += __shfl_xor(s, off);
        s2 += __shfl_xor(s2, off);
    }
    __shared__ float ws1[4], ws2[4];
    int wid = tid >> 6;
    if ((tid & 63) == 0) { ws1[wid] = s; ws2[wid] = s2; }
    __syncthreads();
    s = ws1[0] + ws1[1] + ws1[2] + ws1[3];
    s2 = ws2[0] + ws2[1] + ws2[2] + ws2[3];
    float mu = s * (1.f / 768.f);
    float var = s2 * (1.f / 768.f) - mu * mu;
    float r = rsqrtf(var + 1e-6f);
    bf16_t* orow = out + (size_t)n * 768;
    orow[tid]       = (bf16_t)((x0 - mu) * r * g[tid]       + b[tid]);
    orow[tid + 256] = (bf16_t)((x1 - mu) * r * g[tid + 256] + b[tid + 256]);
    orow[tid + 512] = (bf16_t)((x2 - mu) * r * g[tid + 512] + b[tid + 512]);
}

// ---------------------------------------------------------------------------
// QKV GEMM: [4096,2304] = tok_bf16[4096,768] @ qkv_w[2304,768]^T
// Scatter epilogue: q,k -> [12][4096][64] bf16 ; v -> transposed [12][64][4096]
// Grid: (64 m-tiles, 36 n-tiles), 256 threads. BK=64.
// ---------------------------------------------------------------------------
__global__ __launch_bounds__(256) void qkv_gemm(const bf16_t* __restrict__ tokb,
                                                const bf16_t* __restrict__ wq,
                                                bf16_t* __restrict__ qb,
                                                bf16_t* __restrict__ kb,
                                                bf16_t* __restrict__ vtb) {
    const int bm = blockIdx.x;   // 64 token tiles
    const int bn = blockIdx.y;   // 36 output-col tiles
    const int tid = threadIdx.x;

    __shared__ bf16_t At[64][72];
    __shared__ bf16_t Bt[64][72];

    const int rl = tid >> 3;         // 0..31
    const int c8 = (tid & 7) * 8;
    const int lane = tid & 63, wid = tid >> 6, ln = lane & 15, quad = lane >> 4;

    f32x4 acc[4];
    #pragma unroll
    for (int s = 0; s < 4; s++) acc[s] = {0.f, 0.f, 0.f, 0.f};

    for (int kb0 = 0; kb0 < 768; kb0 += 64) {
        __syncthreads();
        #pragma unroll
        for (int p = 0; p < 2; p++) {
            int row = rl + p * 32;
            *(int4*)(&At[row][c8]) = *(const int4*)(tokb + (size_t)(bm * 64 + row) * 768 + kb0 + c8);
            *(int4*)(&Bt[row][c8]) = *(const int4*)(wq   + (size_t)(bn * 64 + row) * 768 + kb0 + c8);
        }
        __syncthreads();
        #pragma unroll
        for (int kk = 0; kk < 2; kk++) {
            bf16x8 af = *(const bf16x8*)(&At[wid * 16 + ln][kk * 32 + quad * 8]);
            #pragma unroll
            for (int s = 0; s < 4; s++) {
                bf16x8 bfr = *(const bf16x8*)(&Bt[s * 16 + ln][kk * 32 + quad * 8]);
                acc[s] = __builtin_amdgcn_mfma_f32_16x16x32_bf16(af, bfr, acc[s], 0, 0, 0);
            }
        }
    }

    const int ncol0 = bn * 64;
    const int sidx = ncol0 / 768;          // 0=q 1=k 2=v (uniform per block)
    const int head = (ncol0 % 768) >> 6;   // uniform per block
    #pragma unroll
    for (int s = 0; s < 4; s++) {
        int dc = s * 16 + ln;
        #pragma unroll
        for (int r = 0; r < 4; r++) {
            int m = bm * 64 + wid * 16 + quad * 4 + r;
            bf16_t val = (bf16_t)acc[s][r];
            if (sidx == 0)      qb[((size_t)(head * 4096 + m)) * 64 + dc] = val;
            else if (sidx == 1) kb[((size_t)(head * 4096 + m)) * 64 + dc] = val;
            else                vtb[((size_t)(head * 64 + dc)) * 4096 + m] = val;
        }
    }
}

// ---------------------------------------------------------------------------
// Flash attention: per block = (64-query tile, head). 4 waves x 16 rows each.
// K/V^T tiles of 64 keys staged in LDS; online softmax; P via LDS relayout.
// Grid: (64 q-tiles, 12 heads), 256 threads.
// ---------------------------------------------------------------------------
__global__ __launch_bounds__(256) void attn_kernel(const bf16_t* __restrict__ qbuf,
                                                   const bf16_t* __restrict__ kbuf,
                                                   const bf16_t* __restrict__ vtbuf,
                                                   float* __restrict__ out) {
    const int h = blockIdx.y;
    const int q0 = blockIdx.x * 64;
    const int tid = threadIdx.x;
    const int wid = tid >> 6;
    const int lane = tid & 63;
    const int ln = lane & 15;
    const int quad = lane >> 4;

    __shared__ bf16_t Kt[64][72];
    __shared__ bf16_t Vt[64][72];
    __shared__ bf16_t Pt[4][16][72];

    // Q fragments (A-operand layout), held in registers for all iterations
    bf16x8 qf[2];
    {
        const int qrow = q0 + wid * 16 + ln;
        const bf16_t* qp = qbuf + ((size_t)(h * 4096 + qrow)) * 64;
        qf[0] = *(const bf16x8*)(qp + quad * 8);
        qf[1] = *(const bf16x8*)(qp + 32 + quad * 8);
    }

    float m_run[4], l_run[4];
    f32x4 acc_o[4];
    #pragma unroll
    for (int r = 0; r < 4; r++) { m_run[r] = -INFINITY; l_run[r] = 0.f; }
    #pragma unroll
    for (int d = 0; d < 4; d++) acc_o[d] = {0.f, 0.f, 0.f, 0.f};

    const int rl = tid >> 3;        // 0..31
    const int c8 = (tid & 7) * 8;

    for (int kt = 0; kt < 64; kt++) {
        const int k0 = kt * 64;
        __syncthreads();   // previous iteration's LDS reads complete
        #pragma unroll
        for (int p = 0; p < 2; p++) {
            int row = rl + p * 32;
            *(int4*)(&Kt[row][c8]) = *(const int4*)(kbuf + ((size_t)(h * 4096 + k0 + row)) * 64 + c8);
            *(int4*)(&Vt[row][c8]) = *(const int4*)(vtbuf + ((size_t)(h * 64 + row)) * 4096 + k0 + c8);
        }
        __syncthreads();

        // S = Q K^T for this wave's 16 query rows x 64 keys
        f32x4 accs[4];
        #pragma unroll
        for (int s = 0; s < 4; s++) {
            bf16x8 kf0 = *(const bf16x8*)(&Kt[s * 16 + ln][quad * 8]);
            bf16x8 kf1 = *(const bf16x8*)(&Kt[s * 16 + ln][32 + quad * 8]);
            f32x4 z = {0.f, 0.f, 0.f, 0.f};
            f32x4 a = __builtin_amdgcn_mfma_f32_16x16x32_bf16(qf[0], kf0, z, 0, 0, 0);
            accs[s] = __builtin_amdgcn_mfma_f32_16x16x32_bf16(qf[1], kf1, a, 0, 0, 0);
        }

        // online softmax per row (row = quad*4 + r; cols = s*16 + ln)
        #pragma unroll
        for (int r = 0; r < 4; r++) {
            float ss0 = accs[0][r] * 0.125f;
            float ss1 = accs[1][r] * 0.125f;
            float ss2 = accs[2][r] * 0.125f;
            float ss3 = accs[3][r] * 0.125f;
            float vmax = fmaxf(fmaxf(ss0, ss1), fmaxf(ss2, ss3));
            vmax = fmaxf(vmax, __shfl_xor(vmax, 1));
            vmax = fmaxf(vmax, __shfl_xor(vmax, 2));
            vmax = fmaxf(vmax, __shfl_xor(vmax, 4));
            vmax = fmaxf(vmax, __shfl_xor(vmax, 8));
            float m_new = fmaxf(m_run[r], vmax);
            float alpha = exp2f((m_run[r] - m_new) * LOG2E);
            float p0 = exp2f((ss0 - m_new) * LOG2E);
            float p1 = exp2f((ss1 - m_new) * LOG2E);
            float p2 = exp2f((ss2 - m_new) * LOG2E);
            float p3 = exp2f((ss3 - m_new) * LOG2E);
            float rs = p0 + p1 + p2 + p3;
            rs += __shfl_xor(rs, 1);
            rs += __shfl_xor(rs, 2);
            rs += __shfl_xor(rs, 4);
            rs += __shfl_xor(rs, 8);
            l_run[r] = l_run[r] * alpha + rs;
            m_run[r] = m_new;
            #pragma unroll
            for (int d = 0; d < 4; d++) acc_o[d][r] *= alpha;
            int prow = quad * 4 + r;
            Pt[wid][prow][0 * 16 + ln] = (bf16_t)p0;
            Pt[wid][prow][1 * 16 + ln] = (bf16_t)p1;
            Pt[wid][prow][2 * 16 + ln] = (bf16_t)p2;
            Pt[wid][prow][3 * 16 + ln] = (bf16_t)p3;
        }
        __syncthreads();   // P writes visible (and lgkmcnt drained)

        // O += P V  (P in A-layout from LDS, V^T rows give B-operand)
        bf16x8 pf0 = *(const bf16x8*)(&Pt[wid][ln][quad * 8]);
        bf16x8 pf1 = *(const bf16x8*)(&Pt[wid][ln][32 + quad * 8]);
        #pragma unroll
        for (int d = 0; d < 4; d++) {
            bf16x8 vf0 = *(const bf16x8*)(&Vt[d * 16 + ln][quad * 8]);
            bf16x8 vf1 = *(const bf16x8*)(&Vt[d * 16 + ln][32 + quad * 8]);
            acc_o[d] = __builtin_amdgcn_mfma_f32_16x16x32_bf16(pf0, vf0, acc_o[d], 0, 0, 0);
            acc_o[d] = __builtin_amdgcn_mfma_f32_16x16x32_bf16(pf1, vf1, acc_o[d], 0, 0, 0);
        }
    }

    // epilogue: out[q, h*64 + dcol] = acc / l
    #pragma unroll
    for (int r = 0; r < 4; r++) {
        float inv = 1.0f / l_run[r];
        int row = q0 + wid * 16 + quad * 4 + r;
        float* op = out + (size_t)row * 768 + h * 64 + ln;
        #pragma unroll
        for (int d = 0; d < 4; d++) op[d * 16] = acc_o[d][r] * inv;
    }
}

// ---------------------------------------------------------------------------
extern "C" void kernel_launch(void* const* d_in, const int* in_sizes, int n_in,
                              void* d_out, int out_size, void* d_ws, size_t ws_size,
                              hipStream_t stream) {
    const float* x      = (const float*)d_in[0];
    const float* proj_w = (const float*)d_in[1];
    const float* proj_b = (const float*)d_in[2];
    const float* ln_g   = (const float*)d_in[3];
    const float* ln_b   = (const float*)d_in[4];
    const float* qkv_w  = (const float*)d_in[5];
    float* out = (float*)d_out;

    char* ws = (char*)d_ws;
    // workspace layout (bytes)
    float*  tok_pre = (float*)(ws + 0);              // 4096*768*4  = 12,582,912
    bf16_t* tok_b   = (bf16_t*)(ws + 12582912);      // 4096*768*2  =  6,291,456
    bf16_t* pw_b    = (bf16_t*)(ws + 18874368);      // 768*256*2   =    393,216
    bf16_t* qw_b    = (bf16_t*)(ws + 19267584);      // 2304*768*2  =  3,538,944
    bf16_t* qbuf    = (bf16_t*)(ws + 22806528);      // 12*4096*64*2 = 6,291,456
    bf16_t* kbuf    = (bf16_t*)(ws + 29097984);      // 6,291,456
    bf16_t* vtbuf   = (bf16_t*)(ws + 35389440);      // 6,291,456  (total ~41.7 MB)

    cvt_kernel<<<192, 256, 0, stream>>>(proj_w, pw_b, 768 * 256 / 4);
    cvt_kernel<<<1728, 256, 0, stream>>>(qkv_w, qw_b, 2304 * 768 / 4);
    patch_gemm<<<dim3(64, 12), 256, 0, stream>>>(x, pw_b, proj_b, tok_pre);
    ln_kernel<<<4096, 256, 0, stream>>>(tok_pre, ln_g, ln_b, tok_b);
    qkv_gemm<<<dim3(64, 36), 256, 0, stream>>>(tok_b, qw_b, qbuf, kbuf, vtbuf);
    attn_kernel<<<dim3(64, 12), 256, 0, stream>>>(qbuf, kbuf, vtbuf, out);
}